// Round 7
// baseline (1141.833 us; speedup 1.0000x reference)
//
#include <hip/hip_runtime.h>

// ---------------------------------------------------------------------------
// MMoE: B=8192, D_IN=1024, E=8, T=4, H1=1024, H2=512, H3=256
// R14 = R13 + two orthogonal, GEMM-math-preserving changes:
//   1) gemm __launch_bounds__(256,4) -> (256,5): LDS 32KB/block x 5 = 160KB
//      = exactly the CU pool; VGPR=64 allows 8 waves/SIMD, so a 5th
//      co-resident block adds 25% more wave-overlap against the per-K-tile
//      vmcnt drain (the known structural stall of this 2-barrier loop).
//   2) combine_kernel vectorized (was 8 scalar bf16 loads/thread from 8192
//      single-row blocks): 8 rows/block, bf16x8 loads (512B contiguous per
//      expert-row), float4 stores. Pure-BW kernel -> ~14us floor.
// GEMM core frozen (R7 structure): 16x16x32 mfma, 128x128 tile, BK=64,
// XOR-swizzled LDS (0 conflicts), XCD-ownership swizzle (e=lin&7).
// Closed paths: 8-phase counted-vmcnt (toolchain drains at s_barrier,
// R8-R11); 32x32x16 mfma (bank conflicts, R12).
// ---------------------------------------------------------------------------

#define B_ROWS 8192
#define D_IN   1024
#define NEXP   8
#define NTASK  4
#define H1     1024
#define H2     512
#define H3     256

typedef __attribute__((ext_vector_type(8))) short bf16x8;
typedef __attribute__((ext_vector_type(4))) float f32x4;

__device__ __forceinline__ unsigned short f2bf(float f) {
    union { float f; unsigned int u; } x; x.f = f;
    unsigned int r = x.u + 0x7fffu + ((x.u >> 16) & 1u);  // RNE
    return (unsigned short)(r >> 16);
}
__device__ __forceinline__ float bf2f(unsigned short u) {
    union { unsigned int u; float f; } x; x.u = ((unsigned int)u) << 16;
    return x.f;
}

__device__ __forceinline__ void gload_lds16(const void* gptr, void* lptr) {
    __builtin_amdgcn_global_load_lds(
        (__attribute__((address_space(1))) void*)gptr,
        (__attribute__((address_space(3))) void*)lptr,
        16, 0, 0);
}

struct __align__(8) us4 { unsigned short x, y, z, w; };

// ---------------------------------------------------------------------------
// prep kernel: one launch does gates+x-convert AND all three weight
// transposes (W [E][K][N] fp32 -> Wt [E][N][K] bf16, 64x64 tiles).
// Flat grid partition (256 threads/block):
//   [0,1024)            gates + x->bf16 convert   (1024 blocks)
//   [1024,3072)         W1 transpose (K=1024,N=1024: 256 blk/expert x 8)
//   [3072,4096)         W2 transpose (K=1024,N=512: 128 blk/expert x 8)
//   [4096,4352)         W3 transpose (K=512, N=256:  32 blk/expert x 8)
// ---------------------------------------------------------------------------
__device__ __forceinline__ void transpose_body(
    unsigned int local, const float* __restrict__ W,
    unsigned short* __restrict__ Wt, int K, int N, float (*tile)[65]) {
    const int kt = K >> 6, nt = N >> 6;       // tiles per dim
    const int bpe = kt * nt;                  // blocks per expert
    const int e  = (int)(local / (unsigned)bpe);
    const int rem = (int)(local % (unsigned)bpe);
    const int k0 = (rem % kt) * 64, n0 = (rem / kt) * 64;
    const float* We = W + (size_t)e * K * N;
    unsigned short* Wte = Wt + (size_t)e * K * N;
    const int tid = threadIdx.x;
    const int tn = tid & 63;             // n within tile (read side)
    const int tk = tid >> 6;             // 0..3
#pragma unroll
    for (int i = 0; i < 16; ++i)
        tile[tk * 16 + i][tn] = We[(size_t)(k0 + tk * 16 + i) * N + n0 + tn];
    __syncthreads();
    const int wk = (tid & 15) * 4;       // k-chunk start (write side)
    const int wn = tid >> 4;             // 0..15
#pragma unroll
    for (int i = 0; i < 4; ++i) {
        const int n = wn + i * 16;
        us4 o;
        o.x = f2bf(tile[wk + 0][n]);
        o.y = f2bf(tile[wk + 1][n]);
        o.z = f2bf(tile[wk + 2][n]);
        o.w = f2bf(tile[wk + 3][n]);
        *(us4*)&Wte[(size_t)(n0 + n) * K + k0 + wk] = o;
    }
}

__global__ void prep_kernel(const float* __restrict__ x,
                            const float* __restrict__ gw,
                            float* __restrict__ gates,
                            unsigned short* __restrict__ xb,
                            const float* __restrict__ W1,
                            unsigned short* __restrict__ w1t,
                            const float* __restrict__ W2,
                            unsigned short* __restrict__ w2t,
                            const float* __restrict__ W3,
                            unsigned short* __restrict__ w3t) {
    __shared__ float tile[64][65];
    const unsigned int bid = blockIdx.x;
    if (bid >= 1024u) {
        if (bid < 3072u)       transpose_body(bid - 1024u, W1, w1t, D_IN, H1, tile);
        else if (bid < 4096u)  transpose_body(bid - 3072u, W2, w2t, H1,   H2, tile);
        else                   transpose_body(bid - 4096u, W3, w3t, H2,   H3, tile);
        return;
    }
    // ---- gates + x->bf16 convert (blocks 0..1023, 8 rows x 32 outputs) ----
    const int tid = threadIdx.x;
    const size_t base = (size_t)bid * 8192 + (size_t)tid * 32;
#pragma unroll
    for (int i = 0; i < 8; ++i) {
        float4 v = *(const float4*)&x[base + i * 4];
        us4 o4;
        o4.x = f2bf(v.x); o4.y = f2bf(v.y); o4.z = f2bf(v.z); o4.w = f2bf(v.w);
        ((us4*)xb)[base / 4 + i] = o4;
    }
    const int o = tid & 31;          // t*8 + e
    const int r = tid >> 5;          // 0..7
    const int b = (int)bid * 8 + r;
    const float* xr = x + (size_t)b * D_IN;
    float acc = 0.f;
    for (int k = 0; k < D_IN; k += 4) {
        float4 xv = *(const float4*)&xr[k];
        acc += xv.x * gw[(k + 0) * 32 + o];
        acc += xv.y * gw[(k + 1) * 32 + o];
        acc += xv.z * gw[(k + 2) * 32 + o];
        acc += xv.w * gw[(k + 3) * 32 + o];
    }
    float m = acc;
    m = fmaxf(m, __shfl_xor(m, 1));
    m = fmaxf(m, __shfl_xor(m, 2));
    m = fmaxf(m, __shfl_xor(m, 4));
    float ex = __expf(acc - m);
    float s = ex;
    s += __shfl_xor(s, 1);
    s += __shfl_xor(s, 2);
    s += __shfl_xor(s, 4);
    gates[(size_t)b * 32 + o] = ex / s;
}

// ---------------------------------------------------------------------------
// GEMM: C[e] = relu(A[e] @ Bt[e]^T + bias[e]) ; all bf16, acc fp32
// A: [M,K] rm (per-expert stride Aes elems), Bt: [N,K] rm, C: [M,N] rm bf16
// block = 256 (4 waves, 2x2), tile 128x128, BK=64, single-buffered.
// XOR-swizzled LDS (chunk c of row r holds global chunk c^(r&7)): 0 conflicts.
// XCD-ownership swizzle: e = lin&7, slot = lin>>3; n = slot & (gy-1),
// m = slot >> log2(gy). Requires gridDim = (M/128, N/128, 8), all pow2.
// launch_bounds(256,5): 5 blocks/CU (LDS 5x32KB = 160KB pool), 20 waves/CU.
// ---------------------------------------------------------------------------
__global__ __launch_bounds__(256, 5) void gemm_bias_relu_kernel(
    const unsigned short* __restrict__ A, long long Aes,
    const unsigned short* __restrict__ Bt, long long Bes,
    const float* __restrict__ bias, long long bias_es,
    unsigned short* __restrict__ C, long long Ces,
    int M, int N, int K) {
    __shared__ __align__(16) unsigned short sA[128 * 64];
    __shared__ __align__(16) unsigned short sB[128 * 64];

    const int tid  = threadIdx.x;
    const int lane = tid & 63;
    const int w    = tid >> 6;       // wave 0..3
    const int wr   = w >> 1, wc = w & 1;
    const int quad = lane >> 4, l15 = lane & 15;
    const int r8   = lane >> 3;      // staging row-in-octet 0..7
    const int c8   = lane & 7;       // staging 16B-chunk 0..7
    const int gchunk = c8 ^ r8;      // XOR-swizzled global chunk to fetch

    // XCD-ownership block swizzle
    const unsigned int gy   = gridDim.y;
    const unsigned int lin  = blockIdx.x + gridDim.x * (blockIdx.y + gy * blockIdx.z);
    const unsigned int e    = lin & 7;              // heuristic: lin%8 -> XCD
    const unsigned int slot = lin >> 3;
    const int gysh = __builtin_ctz(gy);
    const int n0 = (int)(slot & (gy - 1)) * 128;    // n fastest within XCD
    const int m0 = (int)(slot >> gysh) * 128;       // m outer

    A    += (size_t)e * Aes;
    Bt   += (size_t)e * Bes;
    bias += (size_t)e * bias_es;
    C    += (size_t)e * Ces;

    // staging: wave w covers A rows [w*32,w*32+32) and B rows [w*32,w*32+32)
    const unsigned short* Abase = A + (size_t)(m0 + w * 32 + r8) * K + gchunk * 8;
    const unsigned short* Bbase = Bt + (size_t)(n0 + w * 32 + r8) * K + gchunk * 8;
    unsigned short* sAw = &sA[(w * 32 + r8) * 64 + c8 * 8];
    unsigned short* sBw = &sB[(w * 32 + r8) * 64 + c8 * 8];

    f32x4 acc[4][4] = {};
    const int swz = l15 & 7;         // read-side XOR (row&7 of fragment rows)

    for (int k0 = 0; k0 < K; k0 += 64) {
#pragma unroll
        for (int q = 0; q < 4; ++q) {
            gload_lds16(Abase + (size_t)(q * 8) * K + k0, sAw + q * 8 * 64);
            gload_lds16(Bbase + (size_t)(q * 8) * K + k0, sBw + q * 8 * 64);
        }
        __syncthreads();

#pragma unroll
        for (int s = 0; s < 2; ++s) {
            const int cs = ((s * 4 + quad) ^ swz) * 8;  // swizzled k-chunk
            bf16x8 af[4], bfv[4];
#pragma unroll
            for (int i = 0; i < 4; ++i)
                af[i] = *(const bf16x8*)&sA[(wr * 64 + i * 16 + l15) * 64 + cs];
#pragma unroll
            for (int j = 0; j < 4; ++j)
                bfv[j] = *(const bf16x8*)&sB[(wc * 64 + j * 16 + l15) * 64 + cs];
#pragma unroll
            for (int i = 0; i < 4; ++i)
#pragma unroll
                for (int j = 0; j < 4; ++j)
                    acc[i][j] = __builtin_amdgcn_mfma_f32_16x16x32_bf16(
                        af[i], bfv[j], acc[i][j], 0, 0, 0);
        }
        __syncthreads();
    }

    // epilogue: C/D layout col=lane&15, row=quad*4+reg
#pragma unroll
    for (int j = 0; j < 4; ++j) {
        const int col = n0 + wc * 64 + j * 16 + l15;
        const float bv = bias[col];
#pragma unroll
        for (int i = 0; i < 4; ++i) {
#pragma unroll
            for (int r = 0; r < 4; ++r) {
                const int row = m0 + wr * 64 + i * 16 + quad * 4 + r;
                float v = acc[i][j][r] + bv;
                v = v > 0.f ? v : 0.f;
                C[(size_t)row * N + col] = f2bf(v);
            }
        }
    }
}

// ---------------------------------------------------------------------------
// combine: out[t][b][d] = sum_e h3[e][b][d] * g[b][t*8+e]
// vectorized: 8 rows/block (1024 blocks), each lane-of-32 covers 8 d's via
// bf16x8 loads (32 lanes x 16B = 512B contiguous per expert-row); float4
// stores x2 per task.
// ---------------------------------------------------------------------------
__global__ void combine_kernel(const unsigned short* __restrict__ h3,
                               const float* __restrict__ gates,
                               float* __restrict__ out) {
    const int tid = threadIdx.x;
    const int r   = tid >> 5;            // row within block 0..7
    const int lz  = tid & 31;            // lane-of-32
    const int b   = blockIdx.x * 8 + r;
    const int d0  = lz * 8;
    const float* g = &gates[(size_t)b * 32];
    float acc[NTASK][8] = {};
#pragma unroll
    for (int e = 0; e < NEXP; ++e) {
        bf16x8 hv = *(const bf16x8*)&h3[((size_t)e * B_ROWS + b) * H3 + d0];
        float ge[NTASK];
#pragma unroll
        for (int t = 0; t < NTASK; ++t) ge[t] = g[t * 8 + e];
#pragma unroll
        for (int k = 0; k < 8; ++k) {
            const float h = bf2f((unsigned short)hv[k]);
#pragma unroll
            for (int t = 0; t < NTASK; ++t) acc[t][k] += h * ge[t];
        }
    }
#pragma unroll
    for (int t = 0; t < NTASK; ++t) {
        float4 o0 = {acc[t][0], acc[t][1], acc[t][2], acc[t][3]};
        float4 o1 = {acc[t][4], acc[t][5], acc[t][6], acc[t][7]};
        float* orow = &out[((size_t)t * B_ROWS + b) * H3 + d0];
        *(float4*)&orow[0] = o0;
        *(float4*)&orow[4] = o1;
    }
}

// ---------------------------------------------------------------------------
// workspace layout (bytes)
// ---------------------------------------------------------------------------
#define OFF_XBF 0u                          // 8192*1024*2      = 16,777,216
#define OFF_W1T 16777216u                   // 8*1024*1024*2    = 16,777,216
#define OFF_W2T 33554432u                   // 8*512*1024*2     =  8,388,608
#define OFF_W3T 41943040u                   // 8*256*512*2      =  2,097,152
#define OFF_G   44040192u                   // 8192*32*4        =  1,048,576
#define OFF_H1  45088768u                   // 8*8192*1024*2    = 134,217,728
#define OFF_H2  179306496u                  // 8*8192*512*2     = 67,108,864
#define OFF_H3  45088768u                   // aliases h1 (h1 dead after L2)
// total required: 246,415,360 bytes

extern "C" void kernel_launch(void* const* d_in, const int* in_sizes, int n_in,
                              void* d_out, int out_size, void* d_ws, size_t ws_size,
                              hipStream_t stream) {
    const float* x  = (const float*)d_in[0];
    const float* W1 = (const float*)d_in[1];
    const float* b1 = (const float*)d_in[2];
    const float* W2 = (const float*)d_in[3];
    const float* b2 = (const float*)d_in[4];
    const float* W3 = (const float*)d_in[5];
    const float* b3 = (const float*)d_in[6];
    const float* gw = (const float*)d_in[7];
    float* out = (float*)d_out;
    char* ws = (char*)d_ws;

    unsigned short* xbf = (unsigned short*)(ws + OFF_XBF);
    unsigned short* w1t = (unsigned short*)(ws + OFF_W1T);
    unsigned short* w2t = (unsigned short*)(ws + OFF_W2T);
    unsigned short* w3t = (unsigned short*)(ws + OFF_W3T);
    float*          gts = (float*)(ws + OFF_G);
    unsigned short* h1  = (unsigned short*)(ws + OFF_H1);
    unsigned short* h2  = (unsigned short*)(ws + OFF_H2);
    unsigned short* h3  = (unsigned short*)(ws + OFF_H3);

    // fused prep: gates/x-convert (first 1024 blocks) + all weight transposes
    prep_kernel<<<dim3(4352), dim3(256), 0, stream>>>(
        x, gw, gts, xbf, W1, w1t, W2, w2t, W3, w3t);

    // expert MLP layers
    gemm_bias_relu_kernel<<<dim3(B_ROWS / 128, H1 / 128, NEXP), dim3(256), 0, stream>>>(
        xbf, 0LL,
        w1t, (long long)H1 * D_IN,
        b1, (long long)H1,
        h1, (long long)B_ROWS * H1,
        B_ROWS, H1, D_IN);
    gemm_bias_relu_kernel<<<dim3(B_ROWS / 128, H2 / 128, NEXP), dim3(256), 0, stream>>>(
        h1, (long long)B_ROWS * H1,
        w2t, (long long)H2 * H1,
        b2, (long long)H2,
        h2, (long long)B_ROWS * H2,
        B_ROWS, H2, H1);
    gemm_bias_relu_kernel<<<dim3(B_ROWS / 128, H3 / 128, NEXP), dim3(256), 0, stream>>>(
        h2, (long long)B_ROWS * H2,
        w3t, (long long)H3 * H2,
        b3, (long long)H3,
        h3, (long long)B_ROWS * H3,
        B_ROWS, H3, H2);

    // gated combine
    combine_kernel<<<dim3(B_ROWS / 8), dim3(256), 0, stream>>>(h3, gts, out);
}

// Round 8
// 431.361 us; speedup vs baseline: 2.6470x; 2.6470x over previous
//
#include <hip/hip_runtime.h>

// ---------------------------------------------------------------------------
// MMoE: B=8192, D_IN=1024, E=8, T=4, H1=1024, H2=512, H3=256
// R15 = R13 (verified 427us) + R14's vectorized combine, with the R14
// occupancy experiment REVERTED:
//   R14 post-mortem: __launch_bounds__(256,5) forced VGPR cap 64->48; the
//   64-VGPR accumulator spilled to scratch (FETCH 110->722MB, WRITE
//   144MB->1.38GB, MfmaUtil 10.8%, GEMM 534us). This kernel needs >=96
//   VGPR; 4 waves/SIMD (VGPR<=128 band) is the max spill-free occupancy.
//   5-block path closed.
// GEMM core frozen (R7 structure): 16x16x32 mfma, 128x128 tile, BK=64,
// XOR-swizzled LDS (0 conflicts), XCD-ownership swizzle, launch_bounds(256,4).
// Closed paths: 8-phase counted-vmcnt (R8-R11: toolchain drains vmcnt at
// s_barrier); 32x32x16 mfma (R12: bank conflicts); 5 blocks/CU (R14: spill).
// ---------------------------------------------------------------------------

#define B_ROWS 8192
#define D_IN   1024
#define NEXP   8
#define NTASK  4
#define H1     1024
#define H2     512
#define H3     256

typedef __attribute__((ext_vector_type(8))) short bf16x8;
typedef __attribute__((ext_vector_type(4))) float f32x4;

__device__ __forceinline__ unsigned short f2bf(float f) {
    union { float f; unsigned int u; } x; x.f = f;
    unsigned int r = x.u + 0x7fffu + ((x.u >> 16) & 1u);  // RNE
    return (unsigned short)(r >> 16);
}
__device__ __forceinline__ float bf2f(unsigned short u) {
    union { unsigned int u; float f; } x; x.u = ((unsigned int)u) << 16;
    return x.f;
}

__device__ __forceinline__ void gload_lds16(const void* gptr, void* lptr) {
    __builtin_amdgcn_global_load_lds(
        (__attribute__((address_space(1))) void*)gptr,
        (__attribute__((address_space(3))) void*)lptr,
        16, 0, 0);
}

struct __align__(8) us4 { unsigned short x, y, z, w; };

// ---------------------------------------------------------------------------
// prep kernel: one launch does gates+x-convert AND all three weight
// transposes (W [E][K][N] fp32 -> Wt [E][N][K] bf16, 64x64 tiles).
// Flat grid partition (256 threads/block):
//   [0,1024)            gates + x->bf16 convert   (1024 blocks)
//   [1024,3072)         W1 transpose (K=1024,N=1024: 256 blk/expert x 8)
//   [3072,4096)         W2 transpose (K=1024,N=512: 128 blk/expert x 8)
//   [4096,4352)         W3 transpose (K=512, N=256:  32 blk/expert x 8)
// ---------------------------------------------------------------------------
__device__ __forceinline__ void transpose_body(
    unsigned int local, const float* __restrict__ W,
    unsigned short* __restrict__ Wt, int K, int N, float (*tile)[65]) {
    const int kt = K >> 6, nt = N >> 6;       // tiles per dim
    const int bpe = kt * nt;                  // blocks per expert
    const int e  = (int)(local / (unsigned)bpe);
    const int rem = (int)(local % (unsigned)bpe);
    const int k0 = (rem % kt) * 64, n0 = (rem / kt) * 64;
    const float* We = W + (size_t)e * K * N;
    unsigned short* Wte = Wt + (size_t)e * K * N;
    const int tid = threadIdx.x;
    const int tn = tid & 63;             // n within tile (read side)
    const int tk = tid >> 6;             // 0..3
#pragma unroll
    for (int i = 0; i < 16; ++i)
        tile[tk * 16 + i][tn] = We[(size_t)(k0 + tk * 16 + i) * N + n0 + tn];
    __syncthreads();
    const int wk = (tid & 15) * 4;       // k-chunk start (write side)
    const int wn = tid >> 4;             // 0..15
#pragma unroll
    for (int i = 0; i < 4; ++i) {
        const int n = wn + i * 16;
        us4 o;
        o.x = f2bf(tile[wk + 0][n]);
        o.y = f2bf(tile[wk + 1][n]);
        o.z = f2bf(tile[wk + 2][n]);
        o.w = f2bf(tile[wk + 3][n]);
        *(us4*)&Wte[(size_t)(n0 + n) * K + k0 + wk] = o;
    }
}

__global__ void prep_kernel(const float* __restrict__ x,
                            const float* __restrict__ gw,
                            float* __restrict__ gates,
                            unsigned short* __restrict__ xb,
                            const float* __restrict__ W1,
                            unsigned short* __restrict__ w1t,
                            const float* __restrict__ W2,
                            unsigned short* __restrict__ w2t,
                            const float* __restrict__ W3,
                            unsigned short* __restrict__ w3t) {
    __shared__ float tile[64][65];
    const unsigned int bid = blockIdx.x;
    if (bid >= 1024u) {
        if (bid < 3072u)       transpose_body(bid - 1024u, W1, w1t, D_IN, H1, tile);
        else if (bid < 4096u)  transpose_body(bid - 3072u, W2, w2t, H1,   H2, tile);
        else                   transpose_body(bid - 4096u, W3, w3t, H2,   H3, tile);
        return;
    }
    // ---- gates + x->bf16 convert (blocks 0..1023, 8 rows x 32 outputs) ----
    const int tid = threadIdx.x;
    const size_t base = (size_t)bid * 8192 + (size_t)tid * 32;
#pragma unroll
    for (int i = 0; i < 8; ++i) {
        float4 v = *(const float4*)&x[base + i * 4];
        us4 o4;
        o4.x = f2bf(v.x); o4.y = f2bf(v.y); o4.z = f2bf(v.z); o4.w = f2bf(v.w);
        ((us4*)xb)[base / 4 + i] = o4;
    }
    const int o = tid & 31;          // t*8 + e
    const int r = tid >> 5;          // 0..7
    const int b = (int)bid * 8 + r;
    const float* xr = x + (size_t)b * D_IN;
    float acc = 0.f;
    for (int k = 0; k < D_IN; k += 4) {
        float4 xv = *(const float4*)&xr[k];
        acc += xv.x * gw[(k + 0) * 32 + o];
        acc += xv.y * gw[(k + 1) * 32 + o];
        acc += xv.z * gw[(k + 2) * 32 + o];
        acc += xv.w * gw[(k + 3) * 32 + o];
    }
    float m = acc;
    m = fmaxf(m, __shfl_xor(m, 1));
    m = fmaxf(m, __shfl_xor(m, 2));
    m = fmaxf(m, __shfl_xor(m, 4));
    float ex = __expf(acc - m);
    float s = ex;
    s += __shfl_xor(s, 1);
    s += __shfl_xor(s, 2);
    s += __shfl_xor(s, 4);
    gates[(size_t)b * 32 + o] = ex / s;
}

// ---------------------------------------------------------------------------
// GEMM: C[e] = relu(A[e] @ Bt[e]^T + bias[e]) ; all bf16, acc fp32
// A: [M,K] rm (per-expert stride Aes elems), Bt: [N,K] rm, C: [M,N] rm bf16
// block = 256 (4 waves, 2x2), tile 128x128, BK=64, single-buffered.
// XOR-swizzled LDS (chunk c of row r holds global chunk c^(r&7)): 0 conflicts.
// XCD-ownership swizzle: e = lin&7, slot = lin>>3; n = slot & (gy-1),
// m = slot >> log2(gy). Requires gridDim = (M/128, N/128, 8), all pow2.
// launch_bounds(256,4): 4 blocks/CU, 16 waves/CU — max spill-free occupancy.
// ---------------------------------------------------------------------------
__global__ __launch_bounds__(256, 4) void gemm_bias_relu_kernel(
    const unsigned short* __restrict__ A, long long Aes,
    const unsigned short* __restrict__ Bt, long long Bes,
    const float* __restrict__ bias, long long bias_es,
    unsigned short* __restrict__ C, long long Ces,
    int M, int N, int K) {
    __shared__ __align__(16) unsigned short sA[128 * 64];
    __shared__ __align__(16) unsigned short sB[128 * 64];

    const int tid  = threadIdx.x;
    const int lane = tid & 63;
    const int w    = tid >> 6;       // wave 0..3
    const int wr   = w >> 1, wc = w & 1;
    const int quad = lane >> 4, l15 = lane & 15;
    const int r8   = lane >> 3;      // staging row-in-octet 0..7
    const int c8   = lane & 7;       // staging 16B-chunk 0..7
    const int gchunk = c8 ^ r8;      // XOR-swizzled global chunk to fetch

    // XCD-ownership block swizzle
    const unsigned int gy   = gridDim.y;
    const unsigned int lin  = blockIdx.x + gridDim.x * (blockIdx.y + gy * blockIdx.z);
    const unsigned int e    = lin & 7;              // heuristic: lin%8 -> XCD
    const unsigned int slot = lin >> 3;
    const int gysh = __builtin_ctz(gy);
    const int n0 = (int)(slot & (gy - 1)) * 128;    // n fastest within XCD
    const int m0 = (int)(slot >> gysh) * 128;       // m outer

    A    += (size_t)e * Aes;
    Bt   += (size_t)e * Bes;
    bias += (size_t)e * bias_es;
    C    += (size_t)e * Ces;

    // staging: wave w covers A rows [w*32,w*32+32) and B rows [w*32,w*32+32)
    const unsigned short* Abase = A + (size_t)(m0 + w * 32 + r8) * K + gchunk * 8;
    const unsigned short* Bbase = Bt + (size_t)(n0 + w * 32 + r8) * K + gchunk * 8;
    unsigned short* sAw = &sA[(w * 32 + r8) * 64 + c8 * 8];
    unsigned short* sBw = &sB[(w * 32 + r8) * 64 + c8 * 8];

    f32x4 acc[4][4] = {};
    const int swz = l15 & 7;         // read-side XOR (row&7 of fragment rows)

    for (int k0 = 0; k0 < K; k0 += 64) {
#pragma unroll
        for (int q = 0; q < 4; ++q) {
            gload_lds16(Abase + (size_t)(q * 8) * K + k0, sAw + q * 8 * 64);
            gload_lds16(Bbase + (size_t)(q * 8) * K + k0, sBw + q * 8 * 64);
        }
        __syncthreads();

#pragma unroll
        for (int s = 0; s < 2; ++s) {
            const int cs = ((s * 4 + quad) ^ swz) * 8;  // swizzled k-chunk
            bf16x8 af[4], bfv[4];
#pragma unroll
            for (int i = 0; i < 4; ++i)
                af[i] = *(const bf16x8*)&sA[(wr * 64 + i * 16 + l15) * 64 + cs];
#pragma unroll
            for (int j = 0; j < 4; ++j)
                bfv[j] = *(const bf16x8*)&sB[(wc * 64 + j * 16 + l15) * 64 + cs];
#pragma unroll
            for (int i = 0; i < 4; ++i)
#pragma unroll
                for (int j = 0; j < 4; ++j)
                    acc[i][j] = __builtin_amdgcn_mfma_f32_16x16x32_bf16(
                        af[i], bfv[j], acc[i][j], 0, 0, 0);
        }
        __syncthreads();
    }

    // epilogue: C/D layout col=lane&15, row=quad*4+reg
#pragma unroll
    for (int j = 0; j < 4; ++j) {
        const int col = n0 + wc * 64 + j * 16 + l15;
        const float bv = bias[col];
#pragma unroll
        for (int i = 0; i < 4; ++i) {
#pragma unroll
            for (int r = 0; r < 4; ++r) {
                const int row = m0 + wr * 64 + i * 16 + quad * 4 + r;
                float v = acc[i][j][r] + bv;
                v = v > 0.f ? v : 0.f;
                C[(size_t)row * N + col] = f2bf(v);
            }
        }
    }
}

// ---------------------------------------------------------------------------
// combine: out[t][b][d] = sum_e h3[e][b][d] * g[b][t*8+e]
// vectorized: 8 rows/block (1024 blocks), each lane-of-32 covers 8 d's via
// bf16x8 loads (32 lanes x 16B = 512B contiguous per expert-row); float4
// stores x2 per task.
// ---------------------------------------------------------------------------
__global__ void combine_kernel(const unsigned short* __restrict__ h3,
                               const float* __restrict__ gates,
                               float* __restrict__ out) {
    const int tid = threadIdx.x;
    const int r   = tid >> 5;            // row within block 0..7
    const int lz  = tid & 31;            // lane-of-32
    const int b   = blockIdx.x * 8 + r;
    const int d0  = lz * 8;
    const float* g = &gates[(size_t)b * 32];
    float acc[NTASK][8] = {};
#pragma unroll
    for (int e = 0; e < NEXP; ++e) {
        bf16x8 hv = *(const bf16x8*)&h3[((size_t)e * B_ROWS + b) * H3 + d0];
        float ge[NTASK];
#pragma unroll
        for (int t = 0; t < NTASK; ++t) ge[t] = g[t * 8 + e];
#pragma unroll
        for (int k = 0; k < 8; ++k) {
            const float h = bf2f((unsigned short)hv[k]);
#pragma unroll
            for (int t = 0; t < NTASK; ++t) acc[t][k] += h * ge[t];
        }
    }
#pragma unroll
    for (int t = 0; t < NTASK; ++t) {
        float4 o0 = {acc[t][0], acc[t][1], acc[t][2], acc[t][3]};
        float4 o1 = {acc[t][4], acc[t][5], acc[t][6], acc[t][7]};
        float* orow = &out[((size_t)t * B_ROWS + b) * H3 + d0];
        *(float4*)&orow[0] = o0;
        *(float4*)&orow[4] = o1;
    }
}

// ---------------------------------------------------------------------------
// workspace layout (bytes)
// ---------------------------------------------------------------------------
#define OFF_XBF 0u                          // 8192*1024*2      = 16,777,216
#define OFF_W1T 16777216u                   // 8*1024*1024*2    = 16,777,216
#define OFF_W2T 33554432u                   // 8*512*1024*2     =  8,388,608
#define OFF_W3T 41943040u                   // 8*256*512*2      =  2,097,152
#define OFF_G   44040192u                   // 8192*32*4        =  1,048,576
#define OFF_H1  45088768u                   // 8*8192*1024*2    = 134,217,728
#define OFF_H2  179306496u                  // 8*8192*512*2     = 67,108,864
#define OFF_H3  45088768u                   // aliases h1 (h1 dead after L2)
// total required: 246,415,360 bytes

extern "C" void kernel_launch(void* const* d_in, const int* in_sizes, int n_in,
                              void* d_out, int out_size, void* d_ws, size_t ws_size,
                              hipStream_t stream) {
    const float* x  = (const float*)d_in[0];
    const float* W1 = (const float*)d_in[1];
    const float* b1 = (const float*)d_in[2];
    const float* W2 = (const float*)d_in[3];
    const float* b2 = (const float*)d_in[4];
    const float* W3 = (const float*)d_in[5];
    const float* b3 = (const float*)d_in[6];
    const float* gw = (const float*)d_in[7];
    float* out = (float*)d_out;
    char* ws = (char*)d_ws;

    unsigned short* xbf = (unsigned short*)(ws + OFF_XBF);
    unsigned short* w1t = (unsigned short*)(ws + OFF_W1T);
    unsigned short* w2t = (unsigned short*)(ws + OFF_W2T);
    unsigned short* w3t = (unsigned short*)(ws + OFF_W3T);
    float*          gts = (float*)(ws + OFF_G);
    unsigned short* h1  = (unsigned short*)(ws + OFF_H1);
    unsigned short* h2  = (unsigned short*)(ws + OFF_H2);
    unsigned short* h3  = (unsigned short*)(ws + OFF_H3);

    // fused prep: gates/x-convert (first 1024 blocks) + all weight transposes
    prep_kernel<<<dim3(4352), dim3(256), 0, stream>>>(
        x, gw, gts, xbf, W1, w1t, W2, w2t, W3, w3t);

    // expert MLP layers
    gemm_bias_relu_kernel<<<dim3(B_ROWS / 128, H1 / 128, NEXP), dim3(256), 0, stream>>>(
        xbf, 0LL,
        w1t, (long long)H1 * D_IN,
        b1, (long long)H1,
        h1, (long long)B_ROWS * H1,
        B_ROWS, H1, D_IN);
    gemm_bias_relu_kernel<<<dim3(B_ROWS / 128, H2 / 128, NEXP), dim3(256), 0, stream>>>(
        h1, (long long)B_ROWS * H1,
        w2t, (long long)H2 * H1,
        b2, (long long)H2,
        h2, (long long)B_ROWS * H2,
        B_ROWS, H2, H1);
    gemm_bias_relu_kernel<<<dim3(B_ROWS / 128, H3 / 128, NEXP), dim3(256), 0, stream>>>(
        h2, (long long)B_ROWS * H2,
        w3t, (long long)H3 * H2,
        b3, (long long)H3,
        h3, (long long)B_ROWS * H3,
        B_ROWS, H3, H2);

    // gated combine
    combine_kernel<<<dim3(B_ROWS / 8), dim3(256), 0, stream>>>(h3, gts, out);
}

// Round 9
// 402.297 us; speedup vs baseline: 2.8383x; 1.0722x over previous
//
#include <hip/hip_runtime.h>

// ---------------------------------------------------------------------------
// MMoE: B=8192, D_IN=1024, E=8, T=4, H1=1024, H2=512, H3=256
// R16 = R15 with prep-kernel improvements only (GEMM/combine frozen):
//   1) gates sub-kernel staged x in LDS: conversion pass writes the block's
//      8 rows (32KB) to LDS with 16B-chunk swizzle c^(tid&7) (optimal
//      8-phase b128 writes; reads are half-wave broadcast). Kills the 32x
//      re-read of x from L2 (~1 GB/iter).
//   2) transpose write side widened to 16B us8 stores (8 thr x 16B = 128B
//      per row-segment; LDS reads stay 2-way = free).
// Closed paths: 8-phase counted-vmcnt (R8-R11: toolchain drains vmcnt at
// s_barrier); 32x32x16 mfma (R12: bank conflicts); 5 blocks/CU (R14: VGPR
// cap 48 -> accumulator spill).
// GEMM core (R7 structure): 16x16x32 mfma, 128x128 tile, BK=64, XOR-swizzled
// LDS (0 conflicts), XCD-ownership swizzle, launch_bounds(256,4).
// ---------------------------------------------------------------------------

#define B_ROWS 8192
#define D_IN   1024
#define NEXP   8
#define NTASK  4
#define H1     1024
#define H2     512
#define H3     256

typedef __attribute__((ext_vector_type(8))) short bf16x8;
typedef __attribute__((ext_vector_type(4))) float f32x4;

__device__ __forceinline__ unsigned short f2bf(float f) {
    union { float f; unsigned int u; } x; x.f = f;
    unsigned int r = x.u + 0x7fffu + ((x.u >> 16) & 1u);  // RNE
    return (unsigned short)(r >> 16);
}
__device__ __forceinline__ float bf2f(unsigned short u) {
    union { unsigned int u; float f; } x; x.u = ((unsigned int)u) << 16;
    return x.f;
}

__device__ __forceinline__ void gload_lds16(const void* gptr, void* lptr) {
    __builtin_amdgcn_global_load_lds(
        (__attribute__((address_space(1))) void*)gptr,
        (__attribute__((address_space(3))) void*)lptr,
        16, 0, 0);
}

struct __align__(8) us4 { unsigned short x, y, z, w; };
struct __align__(16) us8 { unsigned short s[8]; };

// ---------------------------------------------------------------------------
// prep kernel: one launch does gates+x-convert AND all three weight
// transposes (W [E][K][N] fp32 -> Wt [E][N][K] bf16, 64x64 tiles).
// Flat grid partition (256 threads/block):
//   [0,1024)            gates + x->bf16 convert   (1024 blocks)
//   [1024,3072)         W1 transpose (K=1024,N=1024: 256 blk/expert x 8)
//   [3072,4096)         W2 transpose (K=1024,N=512: 128 blk/expert x 8)
//   [4096,4352)         W3 transpose (K=512, N=256:  32 blk/expert x 8)
// Shared LDS (32KB union): transpose tile[64][65] | gates x-stage xs[8192].
// ---------------------------------------------------------------------------
__device__ __forceinline__ void transpose_body(
    unsigned int local, const float* __restrict__ W,
    unsigned short* __restrict__ Wt, int K, int N, float (*tile)[65]) {
    const int kt = K >> 6, nt = N >> 6;       // tiles per dim
    const int bpe = kt * nt;                  // blocks per expert
    const int e  = (int)(local / (unsigned)bpe);
    const int rem = (int)(local % (unsigned)bpe);
    const int k0 = (rem % kt) * 64, n0 = (rem / kt) * 64;
    const float* We = W + (size_t)e * K * N;
    unsigned short* Wte = Wt + (size_t)e * K * N;
    const int tid = threadIdx.x;
    const int tn = tid & 63;             // n within tile (read side)
    const int tk = tid >> 6;             // 0..3
#pragma unroll
    for (int i = 0; i < 16; ++i)
        tile[tk * 16 + i][tn] = We[(size_t)(k0 + tk * 16 + i) * N + n0 + tn];
    __syncthreads();
    // write side: 8 threads per n-row, 16B us8 stores (128B/row-segment);
    // LDS reads tile[wk+j][n]: bank = 8*(tid&7)+(tid>>3) span -> 2-way, free
    const int wk = (tid & 7) * 8;        // k-chunk start (write side)
    const int wn = tid >> 3;             // 0..31
#pragma unroll
    for (int i = 0; i < 2; ++i) {
        const int n = wn + i * 32;
        us8 o;
#pragma unroll
        for (int j = 0; j < 8; ++j) o.s[j] = f2bf(tile[wk + j][n]);
        *(us8*)&Wte[(size_t)(n0 + n) * K + k0 + wk] = o;
    }
}

__global__ void prep_kernel(const float* __restrict__ x,
                            const float* __restrict__ gw,
                            float* __restrict__ gates,
                            unsigned short* __restrict__ xb,
                            const float* __restrict__ W1,
                            unsigned short* __restrict__ w1t,
                            const float* __restrict__ W2,
                            unsigned short* __restrict__ w2t,
                            const float* __restrict__ W3,
                            unsigned short* __restrict__ w3t) {
    __shared__ __align__(16) float smem[8192];   // 32 KB union
    const unsigned int bid = blockIdx.x;
    if (bid >= 1024u) {
        float (*tile)[65] = (float(*)[65])smem;  // 64*65 = 4160 floats
        if (bid < 3072u)       transpose_body(bid - 1024u, W1, w1t, D_IN, H1, tile);
        else if (bid < 4096u)  transpose_body(bid - 3072u, W2, w2t, H1,   H2, tile);
        else                   transpose_body(bid - 4096u, W3, w3t, H2,   H3, tile);
        return;
    }
    // ---- gates + x->bf16 convert (blocks 0..1023, 8 rows x 32 outputs) ----
    // conversion pass also stages the block's 8 x-rows into LDS (swizzled:
    // thread's 16B chunk c stored at slot c^(tid&7) -> balanced 8-phase b128
    // writes). Gate loop reads LDS (half-wave broadcast) instead of L2.
    float* xs = smem;
    const int tid = threadIdx.x;
    const size_t base = (size_t)bid * 8192 + (size_t)tid * 32;
    const int t7 = tid & 7;
#pragma unroll
    for (int c = 0; c < 8; ++c) {
        float4 v = *(const float4*)&x[base + c * 4];
        us4 o4;
        o4.x = f2bf(v.x); o4.y = f2bf(v.y); o4.z = f2bf(v.z); o4.w = f2bf(v.w);
        *(us4*)&xb[base + c * 4] = o4;
        *(float4*)&xs[tid * 32 + ((c ^ t7) * 4)] = v;
    }
    __syncthreads();
    const int o = tid & 31;          // t*8 + e
    const int r = tid >> 5;          // 0..7
    float acc = 0.f;
    for (int k = 0; k < D_IN; k += 4) {
        // physical LDS index: owner thread = r*32 + (k>>5); its chunk
        // c=(k>>2)&7 lives at slot c^((k>>5)&7) (owner&7 == (k>>5)&7).
        const int hi = k >> 5;
        const int c  = (k >> 2) & 7;
        float4 xv = *(const float4*)&xs[r * 1024 + hi * 32 + ((c ^ (hi & 7)) * 4)];
        acc += xv.x * gw[(k + 0) * 32 + o];
        acc += xv.y * gw[(k + 1) * 32 + o];
        acc += xv.z * gw[(k + 2) * 32 + o];
        acc += xv.w * gw[(k + 3) * 32 + o];
    }
    const int b = (int)bid * 8 + r;
    float m = acc;
    m = fmaxf(m, __shfl_xor(m, 1));
    m = fmaxf(m, __shfl_xor(m, 2));
    m = fmaxf(m, __shfl_xor(m, 4));
    float ex = __expf(acc - m);
    float s = ex;
    s += __shfl_xor(s, 1);
    s += __shfl_xor(s, 2);
    s += __shfl_xor(s, 4);
    gates[(size_t)b * 32 + o] = ex / s;
}

// ---------------------------------------------------------------------------
// GEMM: C[e] = relu(A[e] @ Bt[e]^T + bias[e]) ; all bf16, acc fp32
// A: [M,K] rm (per-expert stride Aes elems), Bt: [N,K] rm, C: [M,N] rm bf16
// block = 256 (4 waves, 2x2), tile 128x128, BK=64, single-buffered.
// XOR-swizzled LDS (chunk c of row r holds global chunk c^(r&7)): 0 conflicts.
// XCD-ownership swizzle: e = lin&7, slot = lin>>3; n = slot & (gy-1),
// m = slot >> log2(gy). Requires gridDim = (M/128, N/128, 8), all pow2.
// launch_bounds(256,4): 4 blocks/CU, 16 waves/CU — max spill-free occupancy.
// ---------------------------------------------------------------------------
__global__ __launch_bounds__(256, 4) void gemm_bias_relu_kernel(
    const unsigned short* __restrict__ A, long long Aes,
    const unsigned short* __restrict__ Bt, long long Bes,
    const float* __restrict__ bias, long long bias_es,
    unsigned short* __restrict__ C, long long Ces,
    int M, int N, int K) {
    __shared__ __align__(16) unsigned short sA[128 * 64];
    __shared__ __align__(16) unsigned short sB[128 * 64];

    const int tid  = threadIdx.x;
    const int lane = tid & 63;
    const int w    = tid >> 6;       // wave 0..3
    const int wr   = w >> 1, wc = w & 1;
    const int quad = lane >> 4, l15 = lane & 15;
    const int r8   = lane >> 3;      // staging row-in-octet 0..7
    const int c8   = lane & 7;       // staging 16B-chunk 0..7
    const int gchunk = c8 ^ r8;      // XOR-swizzled global chunk to fetch

    // XCD-ownership block swizzle
    const unsigned int gy   = gridDim.y;
    const unsigned int lin  = blockIdx.x + gridDim.x * (blockIdx.y + gy * blockIdx.z);
    const unsigned int e    = lin & 7;              // heuristic: lin%8 -> XCD
    const unsigned int slot = lin >> 3;
    const int gysh = __builtin_ctz(gy);
    const int n0 = (int)(slot & (gy - 1)) * 128;    // n fastest within XCD
    const int m0 = (int)(slot >> gysh) * 128;       // m outer

    A    += (size_t)e * Aes;
    Bt   += (size_t)e * Bes;
    bias += (size_t)e * bias_es;
    C    += (size_t)e * Ces;

    // staging: wave w covers A rows [w*32,w*32+32) and B rows [w*32,w*32+32)
    const unsigned short* Abase = A + (size_t)(m0 + w * 32 + r8) * K + gchunk * 8;
    const unsigned short* Bbase = Bt + (size_t)(n0 + w * 32 + r8) * K + gchunk * 8;
    unsigned short* sAw = &sA[(w * 32 + r8) * 64 + c8 * 8];
    unsigned short* sBw = &sB[(w * 32 + r8) * 64 + c8 * 8];

    f32x4 acc[4][4] = {};
    const int swz = l15 & 7;         // read-side XOR (row&7 of fragment rows)

    for (int k0 = 0; k0 < K; k0 += 64) {
#pragma unroll
        for (int q = 0; q < 4; ++q) {
            gload_lds16(Abase + (size_t)(q * 8) * K + k0, sAw + q * 8 * 64);
            gload_lds16(Bbase + (size_t)(q * 8) * K + k0, sBw + q * 8 * 64);
        }
        __syncthreads();

#pragma unroll
        for (int s = 0; s < 2; ++s) {
            const int cs = ((s * 4 + quad) ^ swz) * 8;  // swizzled k-chunk
            bf16x8 af[4], bfv[4];
#pragma unroll
            for (int i = 0; i < 4; ++i)
                af[i] = *(const bf16x8*)&sA[(wr * 64 + i * 16 + l15) * 64 + cs];
#pragma unroll
            for (int j = 0; j < 4; ++j)
                bfv[j] = *(const bf16x8*)&sB[(wc * 64 + j * 16 + l15) * 64 + cs];
#pragma unroll
            for (int i = 0; i < 4; ++i)
#pragma unroll
                for (int j = 0; j < 4; ++j)
                    acc[i][j] = __builtin_amdgcn_mfma_f32_16x16x32_bf16(
                        af[i], bfv[j], acc[i][j], 0, 0, 0);
        }
        __syncthreads();
    }

    // epilogue: C/D layout col=lane&15, row=quad*4+reg
#pragma unroll
    for (int j = 0; j < 4; ++j) {
        const int col = n0 + wc * 64 + j * 16 + l15;
        const float bv = bias[col];
#pragma unroll
        for (int i = 0; i < 4; ++i) {
#pragma unroll
            for (int r = 0; r < 4; ++r) {
                const int row = m0 + wr * 64 + i * 16 + quad * 4 + r;
                float v = acc[i][j][r] + bv;
                v = v > 0.f ? v : 0.f;
                C[(size_t)row * N + col] = f2bf(v);
            }
        }
    }
}

// ---------------------------------------------------------------------------
// combine: out[t][b][d] = sum_e h3[e][b][d] * g[b][t*8+e]
// vectorized: 8 rows/block (1024 blocks), each lane-of-32 covers 8 d's via
// bf16x8 loads (32 lanes x 16B = 512B contiguous per expert-row); float4
// stores x2 per task.
// ---------------------------------------------------------------------------
__global__ void combine_kernel(const unsigned short* __restrict__ h3,
                               const float* __restrict__ gates,
                               float* __restrict__ out) {
    const int tid = threadIdx.x;
    const int r   = tid >> 5;            // row within block 0..7
    const int lz  = tid & 31;            // lane-of-32
    const int b   = blockIdx.x * 8 + r;
    const int d0  = lz * 8;
    const float* g = &gates[(size_t)b * 32];
    float acc[NTASK][8] = {};
#pragma unroll
    for (int e = 0; e < NEXP; ++e) {
        bf16x8 hv = *(const bf16x8*)&h3[((size_t)e * B_ROWS + b) * H3 + d0];
        float ge[NTASK];
#pragma unroll
        for (int t = 0; t < NTASK; ++t) ge[t] = g[t * 8 + e];
#pragma unroll
        for (int k = 0; k < 8; ++k) {
            const float h = bf2f((unsigned short)hv[k]);
#pragma unroll
            for (int t = 0; t < NTASK; ++t) acc[t][k] += h * ge[t];
        }
    }
#pragma unroll
    for (int t = 0; t < NTASK; ++t) {
        float4 o0 = {acc[t][0], acc[t][1], acc[t][2], acc[t][3]};
        float4 o1 = {acc[t][4], acc[t][5], acc[t][6], acc[t][7]};
        float* orow = &out[((size_t)t * B_ROWS + b) * H3 + d0];
        *(float4*)&orow[0] = o0;
        *(float4*)&orow[4] = o1;
    }
}

// ---------------------------------------------------------------------------
// workspace layout (bytes)
// ---------------------------------------------------------------------------
#define OFF_XBF 0u                          // 8192*1024*2      = 16,777,216
#define OFF_W1T 16777216u                   // 8*1024*1024*2    = 16,777,216
#define OFF_W2T 33554432u                   // 8*512*1024*2     =  8,388,608
#define OFF_W3T 41943040u                   // 8*256*512*2      =  2,097,152
#define OFF_G   44040192u                   // 8192*32*4        =  1,048,576
#define OFF_H1  45088768u                   // 8*8192*1024*2    = 134,217,728
#define OFF_H2  179306496u                  // 8*8192*512*2     = 67,108,864
#define OFF_H3  45088768u                   // aliases h1 (h1 dead after L2)
// total required: 246,415,360 bytes

extern "C" void kernel_launch(void* const* d_in, const int* in_sizes, int n_in,
                              void* d_out, int out_size, void* d_ws, size_t ws_size,
                              hipStream_t stream) {
    const float* x  = (const float*)d_in[0];
    const float* W1 = (const float*)d_in[1];
    const float* b1 = (const float*)d_in[2];
    const float* W2 = (const float*)d_in[3];
    const float* b2 = (const float*)d_in[4];
    const float* W3 = (const float*)d_in[5];
    const float* b3 = (const float*)d_in[6];
    const float* gw = (const float*)d_in[7];
    float* out = (float*)d_out;
    char* ws = (char*)d_ws;

    unsigned short* xbf = (unsigned short*)(ws + OFF_XBF);
    unsigned short* w1t = (unsigned short*)(ws + OFF_W1T);
    unsigned short* w2t = (unsigned short*)(ws + OFF_W2T);
    unsigned short* w3t = (unsigned short*)(ws + OFF_W3T);
    float*          gts = (float*)(ws + OFF_G);
    unsigned short* h1  = (unsigned short*)(ws + OFF_H1);
    unsigned short* h2  = (unsigned short*)(ws + OFF_H2);
    unsigned short* h3  = (unsigned short*)(ws + OFF_H3);

    // fused prep: gates/x-convert (first 1024 blocks) + all weight transposes
    prep_kernel<<<dim3(4352), dim3(256), 0, stream>>>(
        x, gw, gts, xbf, W1, w1t, W2, w2t, W3, w3t);

    // expert MLP layers
    gemm_bias_relu_kernel<<<dim3(B_ROWS / 128, H1 / 128, NEXP), dim3(256), 0, stream>>>(
        xbf, 0LL,
        w1t, (long long)H1 * D_IN,
        b1, (long long)H1,
        h1, (long long)B_ROWS * H1,
        B_ROWS, H1, D_IN);
    gemm_bias_relu_kernel<<<dim3(B_ROWS / 128, H2 / 128, NEXP), dim3(256), 0, stream>>>(
        h1, (long long)B_ROWS * H1,
        w2t, (long long)H2 * H1,
        b2, (long long)H2,
        h2, (long long)B_ROWS * H2,
        B_ROWS, H2, H1);
    gemm_bias_relu_kernel<<<dim3(B_ROWS / 128, H3 / 128, NEXP), dim3(256), 0, stream>>>(
        h2, (long long)B_ROWS * H2,
        w3t, (long long)H3 * H2,
        b3, (long long)H3,
        h3, (long long)B_ROWS * H3,
        B_ROWS, H3, H2);

    // gated combine
    combine_kernel<<<dim3(B_ROWS / 8), dim3(256), 0, stream>>>(h3, gts, out);
}